// Round 5
// baseline (826.389 us; speedup 1.0000x reference)
//
#include <hip/hip_runtime.h>
#include <math.h>

// ---------------- problem constants ----------------
#define NPTS 100000
#define KNB  16
#define NK   1600000            // NPTS*KNB

// output layout (float offsets)
#define OUT_XK   6400000        // after x_out [N,64]
#define OUT_KNN  108800000      // after xk [N,16,64]
#define OUT_PR   110400000      // after knn [N,16]

// workspace layout (float offsets)
#define WS_BNP_RAW 0            // 6   (sum3, ssq3)
#define WS_BN1_RAW 6            // 128 (sum64, ssq64)
#define WS_BN2_RAW 134          // 16  (sum8, ssq8)
#define WS_BNP_SS  160          // 6   (scale3, shift3)
#define WS_WS2     166          // 48  (16x3 shrunk lp_w2)
#define WS_WSB     214          // 16  (shrunk lp_b2)
#define WS_BN1_SS  230          // 128 (scale64, shift64)
#define WS_BN2_SS  358          // 16  (scale8, shift8)
#define WS_SYM     384          // 136*16 symmetrized bilinear weights [pair][o]
#define WS_E       4096         // NK*16
#define WS_T2      25604096     // NK*8
#define WS_XROW    38404096     // NPTS*64
#define WS_X1      44804096     // NPTS*16

#define GRID_NK 3125            // 3125 blocks * 256 thr * 2 iters = 1,600,000
#define NK_STRIDE 800000

// ---------------- kernels ----------------

// per-point precompute: xrow = x@w3^T + b3 (64), X1 = x@w1[:,3:]^T + b1 (16)
__global__ __launch_bounds__(256) void k_pre(
    const float* __restrict__ x, const float* __restrict__ w3,
    const float* __restrict__ b3, const float* __restrict__ w1,
    const float* __restrict__ b1, float* __restrict__ ws)
{
    int n = blockIdx.x * 256 + threadIdx.x;
    if (n >= NPTS) return;
    float xr[64];
    const float4* xp = (const float4*)(x + (size_t)n * 64);
    #pragma unroll
    for (int i = 0; i < 16; ++i) {
        float4 v = xp[i];
        xr[4*i] = v.x; xr[4*i+1] = v.y; xr[4*i+2] = v.z; xr[4*i+3] = v.w;
    }
    float* xrow = ws + WS_XROW;
    for (int c = 0; c < 64; ++c) {
        const float* wr = w3 + c * 64;
        float a0 = b3[c], a1 = 0.f;
        #pragma unroll
        for (int q = 0; q < 64; q += 2) { a0 += wr[q] * xr[q]; a1 += wr[q+1] * xr[q+1]; }
        xrow[(size_t)n * 64 + c] = a0 + a1;
    }
    float* X1 = ws + WS_X1;
    for (int j = 0; j < 16; ++j) {
        const float* wr = w1 + j * 67 + 3;
        float a0 = b1[j], a1 = 0.f;
        #pragma unroll
        for (int q = 0; q < 64; q += 2) { a0 += wr[q] * xr[q]; a1 += wr[q+1] * xr[q+1]; }
        X1[n * 16 + j] = a0 + a1;
    }
}

// symmetrize bilinear weights: S'[pair][o], pair enumerates (i<=j)
__global__ void k_sym(const float* __restrict__ bw, float* __restrict__ ws)
{
    int t = blockIdx.x * 256 + threadIdx.x;
    if (t >= 136 * 16) return;
    int pair = t >> 4, o = t & 15;
    int i = 0, r = pair;
    while (r >= 16 - i) { r -= 16 - i; ++i; }
    int j = i + r;
    float v = bw[o * 256 + i * 16 + j];
    if (i != j) v += bw[o * 256 + j * 16 + i];
    ws[WS_SYM + pair * 16 + o] = v;
}

// main heavy pass (fused with p-stats): writes o_pr, o_knn, e; accumulates BN-p stats.
// LDS-resident bilinear weights + LDS-resident e1; 2 elements per thread.
__global__ __launch_bounds__(256) void k_stage0(
    const float* __restrict__ p, const int* __restrict__ knn,
    const float* __restrict__ w1, const float* __restrict__ bb,
    const float* __restrict__ lpw1, const float* __restrict__ lpb1,
    const float* __restrict__ wsro, float* __restrict__ ws, float* __restrict__ out)
{
    __shared__ float wsym[136 * 16];      // 8.7 KB, broadcast reads
    __shared__ float e1s[2][16][256];     // 32 KB, bank = tid%32 (2-way, free)
    __shared__ float sb[6];
    const float* symw = wsro + WS_SYM;
    const float* X1   = wsro + WS_X1;
    float* e_out = ws + WS_E;
    float* o_knn = out + OUT_KNN;
    float* o_pr  = out + OUT_PR;
    int tid = threadIdx.x;
    if (tid < 6) sb[tid] = 0.f;
    for (int k = tid; k < 136 * 16; k += 256) wsym[k] = symw[k];

    int gid = blockIdx.x * 256 + tid;
    int id0 = gid * 2;
    int n = id0 >> 4;                     // both elements share point n
    float px = p[n*3+0], py = p[n*3+1], pz = p[n*3+2];
    float ps0=0.f, ps1=0.f, ps2=0.f, pq0=0.f, pq1=0.f, pq2=0.f;

    #pragma unroll
    for (int e = 0; e < 2; ++e) {
        int id = id0 + e;
        int idx = knn[id];
        float pr0 = p[idx*3+0] - px;
        float pr1 = p[idx*3+1] - py;
        float pr2 = p[idx*3+2] - pz;
        o_pr[id*3+0] = pr0; o_pr[id*3+1] = pr1; o_pr[id*3+2] = pr2;
        o_knn[id] = (float)idx;
        // BN-p stats on pe = lp_w1 @ p_r + lp_b1
        float v0 = lpb1[0] + lpw1[0]*pr0 + lpw1[1]*pr1 + lpw1[2]*pr2;
        float v1 = lpb1[1] + lpw1[3]*pr0 + lpw1[4]*pr1 + lpw1[5]*pr2;
        float v2 = lpb1[2] + lpw1[6]*pr0 + lpw1[7]*pr1 + lpw1[8]*pr2;
        ps0 += v0; ps1 += v1; ps2 += v2;
        pq0 += v0*v0; pq1 += v1*v1; pq2 += v2*v2;
        // e1 = relu(X1[idx] + Wp @ p_r)
        const float4* xg = (const float4*)(X1 + (size_t)idx * 16);
        #pragma unroll
        for (int h = 0; h < 4; ++h) {
            float4 v = xg[h];
            const float* wr = w1 + (4*h) * 67;
            e1s[e][4*h+0][tid] = fmaxf(v.x + wr[0]*pr0 + wr[1]*pr1 + wr[2]*pr2, 0.f);
            wr += 67;
            e1s[e][4*h+1][tid] = fmaxf(v.y + wr[0]*pr0 + wr[1]*pr1 + wr[2]*pr2, 0.f);
            wr += 67;
            e1s[e][4*h+2][tid] = fmaxf(v.z + wr[0]*pr0 + wr[1]*pr1 + wr[2]*pr2, 0.f);
            wr += 67;
            e1s[e][4*h+3][tid] = fmaxf(v.w + wr[0]*pr0 + wr[1]*pr1 + wr[2]*pr2, 0.f);
        }
    }
    __syncthreads();   // wsym + sb visible

    float acc_a[16], acc_b[16];
    #pragma unroll
    for (int o = 0; o < 16; ++o) { float bo = bb[o]; acc_a[o] = bo; acc_b[o] = bo; }

    int pair = 0;
    #pragma unroll 1
    for (int i = 0; i < 16; ++i) {
        float eai = e1s[0][i][tid];
        float ebi = e1s[1][i][tid];
        #pragma unroll 1
        for (int j = i; j < 16; ++j, ++pair) {
            float eaj = e1s[0][j][tid];
            float ebj = e1s[1][j][tid];
            float ma = eai * eaj, mb = ebi * ebj;
            const float4* wp = (const float4*)(wsym + pair * 16);
            float4 w0v = wp[0], w1v = wp[1], w2v = wp[2], w3v = wp[3];
            acc_a[0]  += w0v.x*ma; acc_a[1]  += w0v.y*ma; acc_a[2]  += w0v.z*ma; acc_a[3]  += w0v.w*ma;
            acc_a[4]  += w1v.x*ma; acc_a[5]  += w1v.y*ma; acc_a[6]  += w1v.z*ma; acc_a[7]  += w1v.w*ma;
            acc_a[8]  += w2v.x*ma; acc_a[9]  += w2v.y*ma; acc_a[10] += w2v.z*ma; acc_a[11] += w2v.w*ma;
            acc_a[12] += w3v.x*ma; acc_a[13] += w3v.y*ma; acc_a[14] += w3v.z*ma; acc_a[15] += w3v.w*ma;
            acc_b[0]  += w0v.x*mb; acc_b[1]  += w0v.y*mb; acc_b[2]  += w0v.z*mb; acc_b[3]  += w0v.w*mb;
            acc_b[4]  += w1v.x*mb; acc_b[5]  += w1v.y*mb; acc_b[6]  += w1v.z*mb; acc_b[7]  += w1v.w*mb;
            acc_b[8]  += w2v.x*mb; acc_b[9]  += w2v.y*mb; acc_b[10] += w2v.z*mb; acc_b[11] += w2v.w*mb;
            acc_b[12] += w3v.x*mb; acc_b[13] += w3v.y*mb; acc_b[14] += w3v.z*mb; acc_b[15] += w3v.w*mb;
        }
    }
    float4* eo = (float4*)(e_out + (size_t)id0 * 16);
    eo[0] = make_float4(acc_a[0],  acc_a[1],  acc_a[2],  acc_a[3]);
    eo[1] = make_float4(acc_a[4],  acc_a[5],  acc_a[6],  acc_a[7]);
    eo[2] = make_float4(acc_a[8],  acc_a[9],  acc_a[10], acc_a[11]);
    eo[3] = make_float4(acc_a[12], acc_a[13], acc_a[14], acc_a[15]);
    eo[4] = make_float4(acc_b[0],  acc_b[1],  acc_b[2],  acc_b[3]);
    eo[5] = make_float4(acc_b[4],  acc_b[5],  acc_b[6],  acc_b[7]);
    eo[6] = make_float4(acc_b[8],  acc_b[9],  acc_b[10], acc_b[11]);
    eo[7] = make_float4(acc_b[12], acc_b[13], acc_b[14], acc_b[15]);

    // BN-p block reduction -> global atomics
    #pragma unroll
    for (int off = 32; off; off >>= 1) {
        ps0 += __shfl_xor(ps0, off); ps1 += __shfl_xor(ps1, off); ps2 += __shfl_xor(ps2, off);
        pq0 += __shfl_xor(pq0, off); pq1 += __shfl_xor(pq1, off); pq2 += __shfl_xor(pq2, off);
    }
    if ((tid & 63) == 0) {
        atomicAdd(&sb[0], ps0); atomicAdd(&sb[1], ps1); atomicAdd(&sb[2], ps2);
        atomicAdd(&sb[3], pq0); atomicAdd(&sb[4], pq1); atomicAdd(&sb[5], pq2);
    }
    __syncthreads();
    if (tid < 6) atomicAdd(&ws[WS_BNP_RAW + tid], sb[tid]);
}

__global__ void k_fin_bnp(float* __restrict__ ws,
    const float* __restrict__ g, const float* __restrict__ b,
    const float* __restrict__ lpw2, const float* __restrict__ lpb2)
{
    int t = threadIdx.x;
    if (t < 3) {
        float mean = ws[WS_BNP_RAW + t] / (float)NK;
        float var  = ws[WS_BNP_RAW + 3 + t] / (float)NK - mean * mean;
        float sc = g[t] * rsqrtf(var + 1e-5f);
        ws[WS_BNP_SS + t] = sc;
        ws[WS_BNP_SS + 3 + t] = b[t] - mean * sc;
    }
    if (t >= 16 && t < 64) {
        int r = t - 16, j = r / 3, d = r % 3;
        ws[WS_WS2 + r] = lpw2[(j)*3+d] + lpw2[(16+j)*3+d] + lpw2[(32+j)*3+d] + lpw2[(48+j)*3+d];
    }
    if (t >= 64 && t < 80) {
        int j = t - 64;
        ws[WS_WSB + j] = lpb2[j] + lpb2[16+j] + lpb2[32+j] + lpb2[48+j];
    }
}

// en builder: en[32] = [e, p_shrink]; recomputes pe from p_r (stored in out)
__device__ __forceinline__ void build_en2(
    const float* __restrict__ e_in, const float* __restrict__ o_pr,
    const float* __restrict__ lpw1, const float* __restrict__ lpb1,
    const float* __restrict__ wsro, int id, float* en)
{
    const float4* ep = (const float4*)(e_in + (size_t)id * 16);
    #pragma unroll
    for (int i = 0; i < 4; ++i) {
        float4 v = ep[i];
        en[4*i] = v.x; en[4*i+1] = v.y; en[4*i+2] = v.z; en[4*i+3] = v.w;
    }
    float pr0 = o_pr[id*3+0], pr1 = o_pr[id*3+1], pr2 = o_pr[id*3+2];
    float v0 = lpb1[0] + lpw1[0]*pr0 + lpw1[1]*pr1 + lpw1[2]*pr2;
    float v1 = lpb1[1] + lpw1[3]*pr0 + lpw1[4]*pr1 + lpw1[5]*pr2;
    float v2 = lpb1[2] + lpw1[6]*pr0 + lpw1[7]*pr1 + lpw1[8]*pr2;
    float q0 = fmaxf(v0*wsro[WS_BNP_SS+0] + wsro[WS_BNP_SS+3], 0.f);
    float q1 = fmaxf(v1*wsro[WS_BNP_SS+1] + wsro[WS_BNP_SS+4], 0.f);
    float q2 = fmaxf(v2*wsro[WS_BNP_SS+2] + wsro[WS_BNP_SS+5], 0.f);
    #pragma unroll
    for (int j = 0; j < 16; ++j) {
        en[16+j] = wsro[WS_WSB+j] + wsro[WS_WS2+j*3]*q0 + wsro[WS_WS2+j*3+1]*q1 + wsro[WS_WS2+j*3+2]*q2;
    }
}

// BN1 stats: h1 = en @ c1^T; c1w staged in LDS (broadcast reads)
__global__ __launch_bounds__(256) void k_stats1(
    const float* __restrict__ wsro, const float* __restrict__ out_ro,
    const float* __restrict__ lpw1, const float* __restrict__ lpb1,
    const float* __restrict__ c1w, float* __restrict__ ws)
{
    __shared__ float c1l[2048];     // 8 KB, [c][32]
    __shared__ float sacc[128];
    int tid = threadIdx.x;
    if (tid < 128) sacc[tid] = 0.f;
    for (int k = tid; k < 512; k += 256)
        ((float4*)c1l)[k] = ((const float4*)c1w)[k];
    __syncthreads();
    const float* e_in = wsro + WS_E;
    const float* o_pr = out_ro + OUT_PR;
    int id0 = blockIdx.x * 256 + tid;
    int id1 = id0 + NK_STRIDE;
    float en0[32], en1[32];
    build_en2(e_in, o_pr, lpw1, lpb1, wsro, id0, en0);
    build_en2(e_in, o_pr, lpw1, lpb1, wsro, id1, en1);
    #pragma unroll 1
    for (int c = 0; c < 64; c += 2) {
        const float* wa = c1l + c * 32;
        const float* wb = wa + 32;
        float hA0=0.f, hB0=0.f, hA1=0.f, hB1=0.f;
        #pragma unroll
        for (int q = 0; q < 32; q += 4) {
            float4 va = *(const float4*)(wa + q);
            float4 vb = *(const float4*)(wb + q);
            hA0 += va.x*en0[q] + va.y*en0[q+1] + va.z*en0[q+2] + va.w*en0[q+3];
            hB0 += vb.x*en0[q] + vb.y*en0[q+1] + vb.z*en0[q+2] + vb.w*en0[q+3];
            hA1 += va.x*en1[q] + va.y*en1[q+1] + va.z*en1[q+2] + va.w*en1[q+3];
            hB1 += vb.x*en1[q] + vb.y*en1[q+1] + vb.z*en1[q+2] + vb.w*en1[q+3];
        }
        float sA = hA0 + hA1, qA = hA0*hA0 + hA1*hA1;
        float sB = hB0 + hB1, qB = hB0*hB0 + hB1*hB1;
        #pragma unroll
        for (int off = 32; off; off >>= 1) {
            sA += __shfl_xor(sA, off); qA += __shfl_xor(qA, off);
            sB += __shfl_xor(sB, off); qB += __shfl_xor(qB, off);
        }
        if ((tid & 63) == 0) {
            atomicAdd(&sacc[c], sA);   atomicAdd(&sacc[64+c], qA);
            atomicAdd(&sacc[c+1], sB); atomicAdd(&sacc[65+c], qB);
        }
    }
    __syncthreads();
    if (tid < 128) atomicAdd(&ws[WS_BN1_RAW + tid], sacc[tid]);
}

__global__ void k_fin_bn1(float* __restrict__ ws, const float* __restrict__ g, const float* __restrict__ b)
{
    int c = threadIdx.x;
    if (c < 64) {
        float mean = ws[WS_BN1_RAW + c] / (float)NK;
        float var  = ws[WS_BN1_RAW + 64 + c] / (float)NK - mean * mean;
        float sc = g[c] * rsqrtf(var + 1e-5f);
        ws[WS_BN1_SS + c] = sc;
        ws[WS_BN1_SS + 64 + c] = b[c] - mean * sc;
    }
}

// stage2: h2 = c2 @ relu(bn1(c1 @ en)); weights staged in LDS
__global__ __launch_bounds__(256) void k_stage2(
    const float* __restrict__ wsro, const float* __restrict__ out_ro,
    const float* __restrict__ lpw1, const float* __restrict__ lpb1,
    const float* __restrict__ c1w, const float* __restrict__ c2w,
    float* __restrict__ ws)
{
    __shared__ float c1l[2048];     // [c][32]
    __shared__ float c2t[512];      // transposed: [c][8]
    __shared__ float sacc[16];
    int tid = threadIdx.x;
    if (tid < 16) sacc[tid] = 0.f;
    for (int k = tid; k < 512; k += 256)
        ((float4*)c1l)[k] = ((const float4*)c1w)[k];
    for (int k = tid; k < 512; k += 256)
        c2t[k] = c2w[(k & 7) * 64 + (k >> 3)];
    __syncthreads();
    float tsum[8] = {0,0,0,0,0,0,0,0}, tssq[8] = {0,0,0,0,0,0,0,0};
    const float* e_in = wsro + WS_E;
    const float* o_pr = out_ro + OUT_PR;
    float* t2 = ws + WS_T2;
    int id = blockIdx.x * 256 + tid;
    #pragma unroll 1
    for (int it = 0; it < 2; ++it, id += NK_STRIDE) {
        float en[32];
        build_en2(e_in, o_pr, lpw1, lpb1, wsro, id, en);
        float t2a[8] = {0,0,0,0,0,0,0,0};
        #pragma unroll 1
        for (int c = 0; c < 64; c += 2) {
            const float* wa = c1l + c * 32;
            const float* wb = wa + 32;
            float h0 = 0.f, h1 = 0.f;
            #pragma unroll
            for (int q = 0; q < 32; q += 4) {
                float4 va = *(const float4*)(wa + q);
                float4 vb = *(const float4*)(wb + q);
                h0 += va.x*en[q] + va.y*en[q+1] + va.z*en[q+2] + va.w*en[q+3];
                h1 += vb.x*en[q] + vb.y*en[q+1] + vb.z*en[q+2] + vb.w*en[q+3];
            }
            h0 = fmaxf(h0 * wsro[WS_BN1_SS + c]     + wsro[WS_BN1_SS + 64 + c], 0.f);
            h1 = fmaxf(h1 * wsro[WS_BN1_SS + c + 1] + wsro[WS_BN1_SS + 65 + c], 0.f);
            float4 ca0 = *(const float4*)(c2t + c*8);
            float4 ca1 = *(const float4*)(c2t + c*8 + 4);
            float4 cb0 = *(const float4*)(c2t + c*8 + 8);
            float4 cb1 = *(const float4*)(c2t + c*8 + 12);
            t2a[0] += h0*ca0.x + h1*cb0.x; t2a[1] += h0*ca0.y + h1*cb0.y;
            t2a[2] += h0*ca0.z + h1*cb0.z; t2a[3] += h0*ca0.w + h1*cb0.w;
            t2a[4] += h0*ca1.x + h1*cb1.x; t2a[5] += h0*ca1.y + h1*cb1.y;
            t2a[6] += h0*ca1.z + h1*cb1.z; t2a[7] += h0*ca1.w + h1*cb1.w;
        }
        float4* t2p = (float4*)(t2 + (size_t)id * 8);
        t2p[0] = make_float4(t2a[0], t2a[1], t2a[2], t2a[3]);
        t2p[1] = make_float4(t2a[4], t2a[5], t2a[6], t2a[7]);
        #pragma unroll
        for (int c2 = 0; c2 < 8; ++c2) { tsum[c2] += t2a[c2]; tssq[c2] += t2a[c2] * t2a[c2]; }
    }
    #pragma unroll
    for (int c2 = 0; c2 < 8; ++c2) {
        float s = tsum[c2], s2 = tssq[c2];
        #pragma unroll
        for (int off = 32; off; off >>= 1) { s += __shfl_xor(s, off); s2 += __shfl_xor(s2, off); }
        if ((tid & 63) == 0) { atomicAdd(&sacc[c2], s); atomicAdd(&sacc[8 + c2], s2); }
    }
    __syncthreads();
    if (tid < 16) atomicAdd(&ws[WS_BN2_RAW + tid], sacc[tid]);
}

__global__ void k_fin_bn2(float* __restrict__ ws, const float* __restrict__ g, const float* __restrict__ b)
{
    int c = threadIdx.x;
    if (c < 8) {
        float mean = ws[WS_BN2_RAW + c] / (float)NK;
        float var  = ws[WS_BN2_RAW + 8 + c] / (float)NK - mean * mean;
        float sc = g[c] * rsqrtf(var + 1e-5f);
        ws[WS_BN2_SS + c] = sc;
        ws[WS_BN2_SS + 8 + c] = b[c] - mean * sc;
    }
}

__global__ __launch_bounds__(128) void k_final(
    const int* __restrict__ knn, const float* __restrict__ wsro,
    const float* __restrict__ c3w, const float* __restrict__ c3b,
    const float* __restrict__ lpw1, const float* __restrict__ lpb1,
    const float* __restrict__ lpw2, const float* __restrict__ lpb2,
    float* __restrict__ out)
{
    int n = blockIdx.x, t = threadIdx.x;
    __shared__ float h2s[16][8], ssm[16][8], wls[16][8], pes[16][3], prs[48], red[128];
    __shared__ int idxs[16];
    const float* t2   = wsro + WS_T2;
    const float* o_pr = out + OUT_PR;
    const float* xrow = wsro + WS_XROW;
    if (t < 16) idxs[t] = knn[n * 16 + t];
    if (t < 48) prs[t] = o_pr[(size_t)n * 48 + t];
    {
        int k = t >> 3, c2 = t & 7;
        float v = t2[(size_t)n * 128 + t];
        h2s[k][c2] = fmaxf(v * wsro[WS_BN2_SS + c2] + wsro[WS_BN2_SS + 8 + c2], 0.f);
    }
    __syncthreads();
    if (t < 48) {
        int k = t / 3, d = t % 3;
        float pe = lpb1[d] + lpw1[d*3+0]*prs[k*3+0] + lpw1[d*3+1]*prs[k*3+1] + lpw1[d*3+2]*prs[k*3+2];
        pes[k][d] = fmaxf(pe * wsro[WS_BNP_SS + d] + wsro[WS_BNP_SS + 3 + d], 0.f);
    }
    {
        int k = t >> 3, cc = t & 7;
        float s = c3b[cc];
        #pragma unroll
        for (int q = 0; q < 8; ++q) s += h2s[k][q] * c3w[cc * 8 + q];
        ssm[k][cc] = s;
    }
    __syncthreads();
    if (t < 8) {
        float m = -1e30f;
        for (int k = 0; k < 16; ++k) m = fmaxf(m, ssm[k][t]);
        float sum = 0.f;
        for (int k = 0; k < 16; ++k) { float ev = __expf(ssm[k][t] - m); wls[k][t] = ev; sum += ev; }
        float inv = 1.f / sum;
        for (int k = 0; k < 16; ++k) wls[k][t] *= inv;
    }
    __syncthreads();
    int c = t & 63, kh = t >> 6;
    float w20 = lpw2[c*3], w21 = lpw2[c*3+1], w22 = lpw2[c*3+2], bc = lpb2[c];
    float acc = 0.f;
    float* out_xk = out + OUT_XK + (size_t)n * 1024;
    #pragma unroll
    for (int i = 0; i < 8; ++i) {
        int k = kh * 8 + i;
        float xv = xrow[(size_t)idxs[k] * 64 + c];
        float pemb = bc + w20 * pes[k][0] + w21 * pes[k][1] + w22 * pes[k][2];
        float val = (xv + pemb) * wls[k][c & 7];
        out_xk[k * 64 + c] = val;
        acc += val;
    }
    red[t] = acc;
    __syncthreads();
    if (t < 64) out[(size_t)n * 64 + t] = red[t] + red[t + 64];
}

// ---------------- launch ----------------
extern "C" void kernel_launch(void* const* d_in, const int* in_sizes, int n_in,
                              void* d_out, int out_size, void* d_ws, size_t ws_size,
                              hipStream_t stream)
{
    (void)in_sizes; (void)n_in; (void)out_size; (void)ws_size;
    const float* p    = (const float*)d_in[0];
    const float* x    = (const float*)d_in[1];
    const int*   knn  = (const int*)  d_in[2];
    const float* w1   = (const float*)d_in[3];
    const float* b1   = (const float*)d_in[4];
    const float* bw   = (const float*)d_in[5];
    const float* bb   = (const float*)d_in[6];
    const float* lpw1 = (const float*)d_in[7];
    const float* lpb1 = (const float*)d_in[8];
    const float* bnpg = (const float*)d_in[9];
    const float* bnpb = (const float*)d_in[10];
    const float* lpw2 = (const float*)d_in[11];
    const float* lpb2 = (const float*)d_in[12];
    const float* c1w  = (const float*)d_in[13];
    const float* bn1g = (const float*)d_in[14];
    const float* bn1b = (const float*)d_in[15];
    const float* c2w  = (const float*)d_in[16];
    const float* bn2g = (const float*)d_in[17];
    const float* bn2b = (const float*)d_in[18];
    const float* c3w  = (const float*)d_in[19];
    const float* c3b  = (const float*)d_in[20];
    const float* w3   = (const float*)d_in[21];
    const float* b3   = (const float*)d_in[22];
    float* out = (float*)d_out;
    float* ws  = (float*)d_ws;

    (void)hipMemsetAsync(ws, 0, 160 * sizeof(float), stream);
    k_pre   <<<(NPTS + 255) / 256, 256, 0, stream>>>(x, w3, b3, w1, b1, ws);
    k_sym   <<<9, 256, 0, stream>>>(bw, ws);
    k_stage0<<<GRID_NK, 256, 0, stream>>>(p, knn, w1, bb, lpw1, lpb1, ws, ws, out);
    k_fin_bnp<<<1, 128, 0, stream>>>(ws, bnpg, bnpb, lpw2, lpb2);
    k_stats1<<<GRID_NK, 256, 0, stream>>>(ws, out, lpw1, lpb1, c1w, ws);
    k_fin_bn1<<<1, 64, 0, stream>>>(ws, bn1g, bn1b);
    k_stage2<<<GRID_NK, 256, 0, stream>>>(ws, out, lpw1, lpb1, c1w, c2w, ws);
    k_fin_bn2<<<1, 64, 0, stream>>>(ws, bn2g, bn2b);
    k_final <<<NPTS, 128, 0, stream>>>(knn, ws, c3w, c3b, lpw1, lpb1, lpw2, lpb2, out);
}

// Round 6
// 715.767 us; speedup vs baseline: 1.1545x; 1.1545x over previous
//
#include <hip/hip_runtime.h>
#include <math.h>

// ---------------- problem constants ----------------
#define NPTS 100000
#define KNB  16
#define NK   1600000            // NPTS*KNB

// output layout (float offsets)
#define OUT_XK   6400000        // after x_out [N,64]
#define OUT_KNN  108800000      // after xk [N,16,64]
#define OUT_PR   110400000      // after knn [N,16]

// workspace layout (float offsets)
#define WS_BNP_RAW 0            // 6   (sum3, ssq3)
#define WS_BN1_RAW 6            // 128 (sum64, ssq64)
#define WS_BN2_RAW 134          // 16  (sum8, ssq8)
#define WS_BNP_SS  160          // 6   (scale3, shift3)
#define WS_WS2     166          // 48  (16x3 shrunk lp_w2)
#define WS_WSB     214          // 16  (shrunk lp_b2)
#define WS_BN1_SS  230          // 128 (scale64, shift64)
#define WS_BN2_SS  358          // 16  (scale8, shift8)
#define WS_SYM     384          // 136*16 symmetrized bilinear weights [pair][o]
#define WS_E       4096         // NK*16
#define WS_T2      25604096     // NK*8
#define WS_XROW    38404096     // NPTS*64
#define WS_X1      44804096     // NPTS*16

#define GRID_NK 3125            // 3125 blocks * 256 thr * 2 iters = 1,600,000
#define NK_STRIDE 800000

// ---------------- kernels ----------------

// per-point precompute: xrow = x@w3^T + b3 (64), X1 = x@w1[:,3:]^T + b1 (16)
__global__ __launch_bounds__(256) void k_pre(
    const float* __restrict__ x, const float* __restrict__ w3,
    const float* __restrict__ b3, const float* __restrict__ w1,
    const float* __restrict__ b1, float* __restrict__ ws)
{
    int n = blockIdx.x * 256 + threadIdx.x;
    if (n >= NPTS) return;
    float xr[64];
    const float4* xp = (const float4*)(x + (size_t)n * 64);
    #pragma unroll
    for (int i = 0; i < 16; ++i) {
        float4 v = xp[i];
        xr[4*i] = v.x; xr[4*i+1] = v.y; xr[4*i+2] = v.z; xr[4*i+3] = v.w;
    }
    float* xrow = ws + WS_XROW;
    for (int c = 0; c < 64; ++c) {
        const float* wr = w3 + c * 64;
        float a0 = b3[c], a1 = 0.f;
        #pragma unroll
        for (int q = 0; q < 64; q += 2) { a0 += wr[q] * xr[q]; a1 += wr[q+1] * xr[q+1]; }
        xrow[(size_t)n * 64 + c] = a0 + a1;
    }
    float* X1 = ws + WS_X1;
    for (int j = 0; j < 16; ++j) {
        const float* wr = w1 + j * 67 + 3;
        float a0 = b1[j], a1 = 0.f;
        #pragma unroll
        for (int q = 0; q < 64; q += 2) { a0 += wr[q] * xr[q]; a1 += wr[q+1] * xr[q+1]; }
        X1[n * 16 + j] = a0 + a1;
    }
}

// symmetrize bilinear weights: S'[pair][o], pair enumerates (i<=j)
__global__ void k_sym(const float* __restrict__ bw, float* __restrict__ ws)
{
    int t = blockIdx.x * 256 + threadIdx.x;
    if (t >= 136 * 16) return;
    int pair = t >> 4, o = t & 15;
    int i = 0, r = pair;
    while (r >= 16 - i) { r -= 16 - i; ++i; }
    int j = i + r;
    float v = bw[o * 256 + i * 16 + j];
    if (i != j) v += bw[o * 256 + j * 16 + i];
    ws[WS_SYM + pair * 16 + o] = v;
}

// main heavy pass (fused with p-stats): writes o_pr, o_knn, e; accumulates BN-p stats.
// LDS-resident bilinear weights + LDS-resident e1; 2 elements per thread.
__global__ __launch_bounds__(256) void k_stage0(
    const float* __restrict__ p, const int* __restrict__ knn,
    const float* __restrict__ w1, const float* __restrict__ bb,
    const float* __restrict__ lpw1, const float* __restrict__ lpb1,
    const float* __restrict__ wsro, float* __restrict__ ws, float* __restrict__ out)
{
    __shared__ float wsym[136 * 16];      // 8.7 KB, broadcast reads feed 68 FMAs each
    __shared__ float e1s[2][16][256];     // 32 KB, bank = tid%32 (2-way, free)
    __shared__ float sb[6];
    const float* symw = wsro + WS_SYM;
    const float* X1   = wsro + WS_X1;
    float* e_out = ws + WS_E;
    float* o_knn = out + OUT_KNN;
    float* o_pr  = out + OUT_PR;
    int tid = threadIdx.x;
    if (tid < 6) sb[tid] = 0.f;
    for (int k = tid; k < 136 * 16; k += 256) wsym[k] = symw[k];

    int gid = blockIdx.x * 256 + tid;
    int id0 = gid * 2;
    int n = id0 >> 4;                     // both elements share point n
    float px = p[n*3+0], py = p[n*3+1], pz = p[n*3+2];
    float ps0=0.f, ps1=0.f, ps2=0.f, pq0=0.f, pq1=0.f, pq2=0.f;

    #pragma unroll
    for (int e = 0; e < 2; ++e) {
        int id = id0 + e;
        int idx = knn[id];
        float pr0 = p[idx*3+0] - px;
        float pr1 = p[idx*3+1] - py;
        float pr2 = p[idx*3+2] - pz;
        o_pr[id*3+0] = pr0; o_pr[id*3+1] = pr1; o_pr[id*3+2] = pr2;
        o_knn[id] = (float)idx;
        // BN-p stats on pe = lp_w1 @ p_r + lp_b1
        float v0 = lpb1[0] + lpw1[0]*pr0 + lpw1[1]*pr1 + lpw1[2]*pr2;
        float v1 = lpb1[1] + lpw1[3]*pr0 + lpw1[4]*pr1 + lpw1[5]*pr2;
        float v2 = lpb1[2] + lpw1[6]*pr0 + lpw1[7]*pr1 + lpw1[8]*pr2;
        ps0 += v0; ps1 += v1; ps2 += v2;
        pq0 += v0*v0; pq1 += v1*v1; pq2 += v2*v2;
        // e1 = relu(X1[idx] + Wp @ p_r)
        const float4* xg = (const float4*)(X1 + (size_t)idx * 16);
        #pragma unroll
        for (int h = 0; h < 4; ++h) {
            float4 v = xg[h];
            const float* wr = w1 + (4*h) * 67;
            e1s[e][4*h+0][tid] = fmaxf(v.x + wr[0]*pr0 + wr[1]*pr1 + wr[2]*pr2, 0.f);
            wr += 67;
            e1s[e][4*h+1][tid] = fmaxf(v.y + wr[0]*pr0 + wr[1]*pr1 + wr[2]*pr2, 0.f);
            wr += 67;
            e1s[e][4*h+2][tid] = fmaxf(v.z + wr[0]*pr0 + wr[1]*pr1 + wr[2]*pr2, 0.f);
            wr += 67;
            e1s[e][4*h+3][tid] = fmaxf(v.w + wr[0]*pr0 + wr[1]*pr1 + wr[2]*pr2, 0.f);
        }
    }
    __syncthreads();   // wsym + sb visible

    float acc_a[16], acc_b[16];
    #pragma unroll
    for (int o = 0; o < 16; ++o) { float bo = bb[o]; acc_a[o] = bo; acc_b[o] = bo; }

    int pair = 0;
    #pragma unroll 1
    for (int i = 0; i < 16; ++i) {
        float eai = e1s[0][i][tid];
        float ebi = e1s[1][i][tid];
        #pragma unroll 1
        for (int j = i; j < 16; ++j, ++pair) {
            float eaj = e1s[0][j][tid];
            float ebj = e1s[1][j][tid];
            float ma = eai * eaj, mb = ebi * ebj;
            const float4* wp = (const float4*)(wsym + pair * 16);
            float4 w0v = wp[0], w1v = wp[1], w2v = wp[2], w3v = wp[3];
            acc_a[0]  += w0v.x*ma; acc_a[1]  += w0v.y*ma; acc_a[2]  += w0v.z*ma; acc_a[3]  += w0v.w*ma;
            acc_a[4]  += w1v.x*ma; acc_a[5]  += w1v.y*ma; acc_a[6]  += w1v.z*ma; acc_a[7]  += w1v.w*ma;
            acc_a[8]  += w2v.x*ma; acc_a[9]  += w2v.y*ma; acc_a[10] += w2v.z*ma; acc_a[11] += w2v.w*ma;
            acc_a[12] += w3v.x*ma; acc_a[13] += w3v.y*ma; acc_a[14] += w3v.z*ma; acc_a[15] += w3v.w*ma;
            acc_b[0]  += w0v.x*mb; acc_b[1]  += w0v.y*mb; acc_b[2]  += w0v.z*mb; acc_b[3]  += w0v.w*mb;
            acc_b[4]  += w1v.x*mb; acc_b[5]  += w1v.y*mb; acc_b[6]  += w1v.z*mb; acc_b[7]  += w1v.w*mb;
            acc_b[8]  += w2v.x*mb; acc_b[9]  += w2v.y*mb; acc_b[10] += w2v.z*mb; acc_b[11] += w2v.w*mb;
            acc_b[12] += w3v.x*mb; acc_b[13] += w3v.y*mb; acc_b[14] += w3v.z*mb; acc_b[15] += w3v.w*mb;
        }
    }
    float4* eo = (float4*)(e_out + (size_t)id0 * 16);
    eo[0] = make_float4(acc_a[0],  acc_a[1],  acc_a[2],  acc_a[3]);
    eo[1] = make_float4(acc_a[4],  acc_a[5],  acc_a[6],  acc_a[7]);
    eo[2] = make_float4(acc_a[8],  acc_a[9],  acc_a[10], acc_a[11]);
    eo[3] = make_float4(acc_a[12], acc_a[13], acc_a[14], acc_a[15]);
    eo[4] = make_float4(acc_b[0],  acc_b[1],  acc_b[2],  acc_b[3]);
    eo[5] = make_float4(acc_b[4],  acc_b[5],  acc_b[6],  acc_b[7]);
    eo[6] = make_float4(acc_b[8],  acc_b[9],  acc_b[10], acc_b[11]);
    eo[7] = make_float4(acc_b[12], acc_b[13], acc_b[14], acc_b[15]);

    // BN-p block reduction -> global atomics
    #pragma unroll
    for (int off = 32; off; off >>= 1) {
        ps0 += __shfl_xor(ps0, off); ps1 += __shfl_xor(ps1, off); ps2 += __shfl_xor(ps2, off);
        pq0 += __shfl_xor(pq0, off); pq1 += __shfl_xor(pq1, off); pq2 += __shfl_xor(pq2, off);
    }
    if ((tid & 63) == 0) {
        atomicAdd(&sb[0], ps0); atomicAdd(&sb[1], ps1); atomicAdd(&sb[2], ps2);
        atomicAdd(&sb[3], pq0); atomicAdd(&sb[4], pq1); atomicAdd(&sb[5], pq2);
    }
    __syncthreads();
    if (tid < 6) atomicAdd(&ws[WS_BNP_RAW + tid], sb[tid]);
}

__global__ void k_fin_bnp(float* __restrict__ ws,
    const float* __restrict__ g, const float* __restrict__ b,
    const float* __restrict__ lpw2, const float* __restrict__ lpb2)
{
    int t = threadIdx.x;
    if (t < 3) {
        float mean = ws[WS_BNP_RAW + t] / (float)NK;
        float var  = ws[WS_BNP_RAW + 3 + t] / (float)NK - mean * mean;
        float sc = g[t] * rsqrtf(var + 1e-5f);
        ws[WS_BNP_SS + t] = sc;
        ws[WS_BNP_SS + 3 + t] = b[t] - mean * sc;
    }
    if (t >= 16 && t < 64) {
        int r = t - 16, j = r / 3, d = r % 3;
        ws[WS_WS2 + r] = lpw2[(j)*3+d] + lpw2[(16+j)*3+d] + lpw2[(32+j)*3+d] + lpw2[(48+j)*3+d];
    }
    if (t >= 64 && t < 80) {
        int j = t - 64;
        ws[WS_WSB + j] = lpb2[j] + lpb2[16+j] + lpb2[32+j] + lpb2[48+j];
    }
}

// en builder: en[32] = [e, p_shrink]; recomputes pe from p_r (stored in out)
__device__ __forceinline__ void build_en2(
    const float* __restrict__ e_in, const float* __restrict__ o_pr,
    const float* __restrict__ lpw1, const float* __restrict__ lpb1,
    const float* __restrict__ wsro, int id, float* en)
{
    const float4* ep = (const float4*)(e_in + (size_t)id * 16);
    #pragma unroll
    for (int i = 0; i < 4; ++i) {
        float4 v = ep[i];
        en[4*i] = v.x; en[4*i+1] = v.y; en[4*i+2] = v.z; en[4*i+3] = v.w;
    }
    float pr0 = o_pr[id*3+0], pr1 = o_pr[id*3+1], pr2 = o_pr[id*3+2];
    float v0 = lpb1[0] + lpw1[0]*pr0 + lpw1[1]*pr1 + lpw1[2]*pr2;
    float v1 = lpb1[1] + lpw1[3]*pr0 + lpw1[4]*pr1 + lpw1[5]*pr2;
    float v2 = lpb1[2] + lpw1[6]*pr0 + lpw1[7]*pr1 + lpw1[8]*pr2;
    float q0 = fmaxf(v0*wsro[WS_BNP_SS+0] + wsro[WS_BNP_SS+3], 0.f);
    float q1 = fmaxf(v1*wsro[WS_BNP_SS+1] + wsro[WS_BNP_SS+4], 0.f);
    float q2 = fmaxf(v2*wsro[WS_BNP_SS+2] + wsro[WS_BNP_SS+5], 0.f);
    #pragma unroll
    for (int j = 0; j < 16; ++j) {
        en[16+j] = wsro[WS_WSB+j] + wsro[WS_WS2+j*3]*q0 + wsro[WS_WS2+j*3+1]*q1 + wsro[WS_WS2+j*3+2]*q2;
    }
}

// BN1 stats: h1 = en @ c1^T, accumulate per-channel sum/ssq
// weights via wave-uniform GLOBAL pointer (s_load / scalar cache — r4 proven form)
__global__ __launch_bounds__(256) void k_stats1(
    const float* __restrict__ wsro, const float* __restrict__ out_ro,
    const float* __restrict__ lpw1, const float* __restrict__ lpb1,
    const float* __restrict__ c1w, float* __restrict__ ws)
{
    __shared__ float sacc[128];
    if (threadIdx.x < 128) sacc[threadIdx.x] = 0.f;
    __syncthreads();
    const float* e_in = wsro + WS_E;
    const float* o_pr = out_ro + OUT_PR;
    int id0 = blockIdx.x * 256 + threadIdx.x;
    int id1 = id0 + NK_STRIDE;
    float en0[32], en1[32];
    build_en2(e_in, o_pr, lpw1, lpb1, wsro, id0, en0);
    build_en2(e_in, o_pr, lpw1, lpb1, wsro, id1, en1);
    #pragma unroll 1
    for (int c = 0; c < 64; c += 2) {
        const float* wa = c1w + c * 32;
        const float* wb = wa + 32;
        float a0=0.f, a1=0.f, b0=0.f, b1=0.f, c0=0.f, c1_=0.f, d0=0.f, d1=0.f;
        #pragma unroll
        for (int q = 0; q < 32; q += 2) {
            a0 += wa[q]*en0[q]; a1 += wa[q+1]*en0[q+1];
            b0 += wb[q]*en0[q]; b1 += wb[q+1]*en0[q+1];
            c0 += wa[q]*en1[q]; c1_ += wa[q+1]*en1[q+1];
            d0 += wb[q]*en1[q]; d1 += wb[q+1]*en1[q+1];
        }
        float hA0 = a0+a1, hB0 = b0+b1, hA1 = c0+c1_, hB1 = d0+d1;
        float sA = hA0 + hA1, qA = hA0*hA0 + hA1*hA1;
        float sB = hB0 + hB1, qB = hB0*hB0 + hB1*hB1;
        #pragma unroll
        for (int off = 32; off; off >>= 1) {
            sA += __shfl_xor(sA, off); qA += __shfl_xor(qA, off);
            sB += __shfl_xor(sB, off); qB += __shfl_xor(qB, off);
        }
        if ((threadIdx.x & 63) == 0) {
            atomicAdd(&sacc[c], sA);   atomicAdd(&sacc[64+c], qA);
            atomicAdd(&sacc[c+1], sB); atomicAdd(&sacc[65+c], qB);
        }
    }
    __syncthreads();
    if (threadIdx.x < 128) atomicAdd(&ws[WS_BN1_RAW + threadIdx.x], sacc[threadIdx.x]);
}

__global__ void k_fin_bn1(float* __restrict__ ws, const float* __restrict__ g, const float* __restrict__ b)
{
    int c = threadIdx.x;
    if (c < 64) {
        float mean = ws[WS_BN1_RAW + c] / (float)NK;
        float var  = ws[WS_BN1_RAW + 64 + c] / (float)NK - mean * mean;
        float sc = g[c] * rsqrtf(var + 1e-5f);
        ws[WS_BN1_SS + c] = sc;
        ws[WS_BN1_SS + 64 + c] = b[c] - mean * sc;
    }
}

// stage2: h2 = c2 @ relu(bn1(c1 @ en)); weights via global pointers (r4 form)
__global__ __launch_bounds__(256) void k_stage2(
    const float* __restrict__ wsro, const float* __restrict__ out_ro,
    const float* __restrict__ lpw1, const float* __restrict__ lpb1,
    const float* __restrict__ c1w, const float* __restrict__ c2w,
    float* __restrict__ ws)
{
    float tsum[8] = {0,0,0,0,0,0,0,0}, tssq[8] = {0,0,0,0,0,0,0,0};
    const float* e_in = wsro + WS_E;
    const float* o_pr = out_ro + OUT_PR;
    float* t2 = ws + WS_T2;
    int id = blockIdx.x * 256 + threadIdx.x;
    #pragma unroll 1
    for (int it = 0; it < 2; ++it, id += NK_STRIDE) {
        float en[32];
        build_en2(e_in, o_pr, lpw1, lpb1, wsro, id, en);
        float t2a[8] = {0,0,0,0,0,0,0,0};
        #pragma unroll 1
        for (int c = 0; c < 64; c += 2) {
            const float* wa = c1w + c * 32;
            const float* wb = wa + 32;
            float a0=0.f, a1=0.f, b0=0.f, b1=0.f;
            #pragma unroll
            for (int q = 0; q < 32; q += 2) {
                a0 += wa[q]*en[q]; a1 += wa[q+1]*en[q+1];
                b0 += wb[q]*en[q]; b1 += wb[q+1]*en[q+1];
            }
            float h0 = fmaxf((a0+a1) * wsro[WS_BN1_SS + c] + wsro[WS_BN1_SS + 64 + c], 0.f);
            float h1 = fmaxf((b0+b1) * wsro[WS_BN1_SS + c+1] + wsro[WS_BN1_SS + 65 + c], 0.f);
            #pragma unroll
            for (int c2 = 0; c2 < 8; ++c2)
                t2a[c2] += h0 * c2w[c2 * 64 + c] + h1 * c2w[c2 * 64 + c + 1];
        }
        float4* t2p = (float4*)(t2 + (size_t)id * 8);
        t2p[0] = make_float4(t2a[0], t2a[1], t2a[2], t2a[3]);
        t2p[1] = make_float4(t2a[4], t2a[5], t2a[6], t2a[7]);
        #pragma unroll
        for (int c2 = 0; c2 < 8; ++c2) { tsum[c2] += t2a[c2]; tssq[c2] += t2a[c2] * t2a[c2]; }
    }
    __shared__ float sacc[16];
    if (threadIdx.x < 16) sacc[threadIdx.x] = 0.f;
    __syncthreads();
    #pragma unroll
    for (int c2 = 0; c2 < 8; ++c2) {
        float s = tsum[c2], s2 = tssq[c2];
        #pragma unroll
        for (int off = 32; off; off >>= 1) { s += __shfl_xor(s, off); s2 += __shfl_xor(s2, off); }
        if ((threadIdx.x & 63) == 0) { atomicAdd(&sacc[c2], s); atomicAdd(&sacc[8 + c2], s2); }
    }
    __syncthreads();
    if (threadIdx.x < 16) atomicAdd(&ws[WS_BN2_RAW + threadIdx.x], sacc[threadIdx.x]);
}

__global__ void k_fin_bn2(float* __restrict__ ws, const float* __restrict__ g, const float* __restrict__ b)
{
    int c = threadIdx.x;
    if (c < 8) {
        float mean = ws[WS_BN2_RAW + c] / (float)NK;
        float var  = ws[WS_BN2_RAW + 8 + c] / (float)NK - mean * mean;
        float sc = g[c] * rsqrtf(var + 1e-5f);
        ws[WS_BN2_SS + c] = sc;
        ws[WS_BN2_SS + 8 + c] = b[c] - mean * sc;
    }
}

__global__ __launch_bounds__(128) void k_final(
    const int* __restrict__ knn, const float* __restrict__ wsro,
    const float* __restrict__ c3w, const float* __restrict__ c3b,
    const float* __restrict__ lpw1, const float* __restrict__ lpb1,
    const float* __restrict__ lpw2, const float* __restrict__ lpb2,
    float* __restrict__ out)
{
    int n = blockIdx.x, t = threadIdx.x;
    __shared__ float h2s[16][8], ssm[16][8], wls[16][8], pes[16][3], prs[48], red[128];
    __shared__ int idxs[16];
    const float* t2   = wsro + WS_T2;
    const float* o_pr = out + OUT_PR;
    const float* xrow = wsro + WS_XROW;
    if (t < 16) idxs[t] = knn[n * 16 + t];
    if (t < 48) prs[t] = o_pr[(size_t)n * 48 + t];
    {
        int k = t >> 3, c2 = t & 7;
        float v = t2[(size_t)n * 128 + t];
        h2s[k][c2] = fmaxf(v * wsro[WS_BN2_SS + c2] + wsro[WS_BN2_SS + 8 + c2], 0.f);
    }
    __syncthreads();
    if (t < 48) {
        int k = t / 3, d = t % 3;
        float pe = lpb1[d] + lpw1[d*3+0]*prs[k*3+0] + lpw1[d*3+1]*prs[k*3+1] + lpw1[d*3+2]*prs[k*3+2];
        pes[k][d] = fmaxf(pe * wsro[WS_BNP_SS + d] + wsro[WS_BNP_SS + 3 + d], 0.f);
    }
    {
        int k = t >> 3, cc = t & 7;
        float s = c3b[cc];
        #pragma unroll
        for (int q = 0; q < 8; ++q) s += h2s[k][q] * c3w[cc * 8 + q];
        ssm[k][cc] = s;
    }
    __syncthreads();
    if (t < 8) {
        float m = -1e30f;
        for (int k = 0; k < 16; ++k) m = fmaxf(m, ssm[k][t]);
        float sum = 0.f;
        for (int k = 0; k < 16; ++k) { float ev = __expf(ssm[k][t] - m); wls[k][t] = ev; sum += ev; }
        float inv = 1.f / sum;
        for (int k = 0; k < 16; ++k) wls[k][t] *= inv;
    }
    __syncthreads();
    int c = t & 63, kh = t >> 6;
    float w20 = lpw2[c*3], w21 = lpw2[c*3+1], w22 = lpw2[c*3+2], bc = lpb2[c];
    float acc = 0.f;
    float* out_xk = out + OUT_XK + (size_t)n * 1024;
    #pragma unroll
    for (int i = 0; i < 8; ++i) {
        int k = kh * 8 + i;
        float xv = xrow[(size_t)idxs[k] * 64 + c];
        float pemb = bc + w20 * pes[k][0] + w21 * pes[k][1] + w22 * pes[k][2];
        float val = (xv + pemb) * wls[k][c & 7];
        out_xk[k * 64 + c] = val;
        acc += val;
    }
    red[t] = acc;
    __syncthreads();
    if (t < 64) out[(size_t)n * 64 + t] = red[t] + red[t + 64];
}

// ---------------- launch ----------------
extern "C" void kernel_launch(void* const* d_in, const int* in_sizes, int n_in,
                              void* d_out, int out_size, void* d_ws, size_t ws_size,
                              hipStream_t stream)
{
    (void)in_sizes; (void)n_in; (void)out_size; (void)ws_size;
    const float* p    = (const float*)d_in[0];
    const float* x    = (const float*)d_in[1];
    const int*   knn  = (const int*)  d_in[2];
    const float* w1   = (const float*)d_in[3];
    const float* b1   = (const float*)d_in[4];
    const float* bw   = (const float*)d_in[5];
    const float* bb   = (const float*)d_in[6];
    const float* lpw1 = (const float*)d_in[7];
    const float* lpb1 = (const float*)d_in[8];
    const float* bnpg = (const float*)d_in[9];
    const float* bnpb = (const float*)d_in[10];
    const float* lpw2 = (const float*)d_in[11];
    const float* lpb2 = (const float*)d_in[12];
    const float* c1w  = (const float*)d_in[13];
    const float* bn1g = (const float*)d_in[14];
    const float* bn1b = (const float*)d_in[15];
    const float* c2w  = (const float*)d_in[16];
    const float* bn2g = (const float*)d_in[17];
    const float* bn2b = (const float*)d_in[18];
    const float* c3w  = (const float*)d_in[19];
    const float* c3b  = (const float*)d_in[20];
    const float* w3   = (const float*)d_in[21];
    const float* b3   = (const float*)d_in[22];
    float* out = (float*)d_out;
    float* ws  = (float*)d_ws;

    (void)hipMemsetAsync(ws, 0, 160 * sizeof(float), stream);
    k_pre   <<<(NPTS + 255) / 256, 256, 0, stream>>>(x, w3, b3, w1, b1, ws);
    k_sym   <<<9, 256, 0, stream>>>(bw, ws);
    k_stage0<<<GRID_NK, 256, 0, stream>>>(p, knn, w1, bb, lpw1, lpb1, ws, ws, out);
    k_fin_bnp<<<1, 128, 0, stream>>>(ws, bnpg, bnpb, lpw2, lpb2);
    k_stats1<<<GRID_NK, 256, 0, stream>>>(ws, out, lpw1, lpb1, c1w, ws);
    k_fin_bn1<<<1, 64, 0, stream>>>(ws, bn1g, bn1b);
    k_stage2<<<GRID_NK, 256, 0, stream>>>(ws, out, lpw1, lpb1, c1w, c2w, ws);
    k_fin_bn2<<<1, 64, 0, stream>>>(ws, bn2g, bn2b);
    k_final <<<NPTS, 128, 0, stream>>>(knn, ws, c3w, c3b, lpw1, lpb1, lpw2, lpb2, out);
}

// Round 7
// 709.902 us; speedup vs baseline: 1.1641x; 1.0083x over previous
//
#include <hip/hip_runtime.h>
#include <math.h>

// ---------------- problem constants ----------------
#define NPTS 100000
#define KNB  16
#define NK   1600000            // NPTS*KNB

// output layout (float offsets)
#define OUT_XK   6400000        // after x_out [N,64]
#define OUT_KNN  108800000      // after xk [N,16,64]
#define OUT_PR   110400000      // after knn [N,16]

// workspace layout (float offsets)
#define WS_BNP_RAW 0            // 6   (sum3, ssq3)
#define WS_BN1_RAW 6            // 128 (sum64, ssq64)
#define WS_BN2_RAW 134          // 16  (sum8, ssq8)
#define WS_BNP_SS  160          // 6   (scale3, shift3)
#define WS_WS2     166          // 48  (16x3 shrunk lp_w2)
#define WS_WSB     214          // 16  (shrunk lp_b2)
#define WS_BN1_SS  230          // 128 (scale64, shift64)
#define WS_BN2_SS  358          // 16  (scale8, shift8)
#define WS_SYM     384          // 136*16 symmetrized bilinear weights [pair][o]
#define WS_C1F     2560         // 64*4: folded {M0,M1,M2,d} per channel (c1 x p-shrink path)
#define WS_C2T     2816         // 64*8: c2 transposed [c][c2]
#define WS_E       4096         // NK*16
#define WS_T2      25604096     // NK*8
#define WS_XROW    38404096     // NPTS*64
#define WS_X1      44804096     // NPTS*16

#define GRID_NK 3125            // 3125 blocks * 256 thr * 2 iters = 1,600,000
#define NK_STRIDE 800000

// ---------------- kernels ----------------

// per-point precompute: xrow = x@w3^T + b3 (64), X1 = x@w1[:,3:]^T + b1 (16)
__global__ __launch_bounds__(256) void k_pre(
    const float* __restrict__ x, const float* __restrict__ w3,
    const float* __restrict__ b3, const float* __restrict__ w1,
    const float* __restrict__ b1, float* __restrict__ ws)
{
    int n = blockIdx.x * 256 + threadIdx.x;
    if (n >= NPTS) return;
    float xr[64];
    const float4* xp = (const float4*)(x + (size_t)n * 64);
    #pragma unroll
    for (int i = 0; i < 16; ++i) {
        float4 v = xp[i];
        xr[4*i] = v.x; xr[4*i+1] = v.y; xr[4*i+2] = v.z; xr[4*i+3] = v.w;
    }
    float* xrow = ws + WS_XROW;
    for (int c = 0; c < 64; ++c) {
        const float* wr = w3 + c * 64;
        float a0 = b3[c], a1 = 0.f;
        #pragma unroll
        for (int q = 0; q < 64; q += 2) { a0 += wr[q] * xr[q]; a1 += wr[q+1] * xr[q+1]; }
        xrow[(size_t)n * 64 + c] = a0 + a1;
    }
    float* X1 = ws + WS_X1;
    for (int j = 0; j < 16; ++j) {
        const float* wr = w1 + j * 67 + 3;
        float a0 = b1[j], a1 = 0.f;
        #pragma unroll
        for (int q = 0; q < 64; q += 2) { a0 += wr[q] * xr[q]; a1 += wr[q+1] * xr[q+1]; }
        X1[n * 16 + j] = a0 + a1;
    }
}

// symmetrize bilinear weights: S'[pair][o], pair enumerates (i<=j)
__global__ void k_sym(const float* __restrict__ bw, float* __restrict__ ws)
{
    int t = blockIdx.x * 256 + threadIdx.x;
    if (t >= 136 * 16) return;
    int pair = t >> 4, o = t & 15;
    int i = 0, r = pair;
    while (r >= 16 - i) { r -= 16 - i; ++i; }
    int j = i + r;
    float v = bw[o * 256 + i * 16 + j];
    if (i != j) v += bw[o * 256 + j * 16 + i];
    ws[WS_SYM + pair * 16 + o] = v;
}

// main heavy pass (fused with p-stats): writes o_pr, o_knn, e; accumulates BN-p stats.
__global__ __launch_bounds__(256) void k_stage0(
    const float* __restrict__ p, const int* __restrict__ knn,
    const float* __restrict__ w1, const float* __restrict__ bb,
    const float* __restrict__ lpw1, const float* __restrict__ lpb1,
    const float* __restrict__ wsro, float* __restrict__ ws, float* __restrict__ out)
{
    __shared__ float wsym[136 * 16];      // 8.7 KB, broadcast reads feed 68 FMAs each
    __shared__ float e1s[2][16][256];     // 32 KB, bank = tid%32 (2-way, free)
    __shared__ float sb[6];
    const float* symw = wsro + WS_SYM;
    const float* X1   = wsro + WS_X1;
    float* e_out = ws + WS_E;
    float* o_knn = out + OUT_KNN;
    float* o_pr  = out + OUT_PR;
    int tid = threadIdx.x;
    if (tid < 6) sb[tid] = 0.f;
    for (int k = tid; k < 136 * 16; k += 256) wsym[k] = symw[k];

    int gid = blockIdx.x * 256 + tid;
    int id0 = gid * 2;
    int n = id0 >> 4;                     // both elements share point n
    float px = p[n*3+0], py = p[n*3+1], pz = p[n*3+2];
    float ps0=0.f, ps1=0.f, ps2=0.f, pq0=0.f, pq1=0.f, pq2=0.f;

    #pragma unroll
    for (int e = 0; e < 2; ++e) {
        int id = id0 + e;
        int idx = knn[id];
        float pr0 = p[idx*3+0] - px;
        float pr1 = p[idx*3+1] - py;
        float pr2 = p[idx*3+2] - pz;
        o_pr[id*3+0] = pr0; o_pr[id*3+1] = pr1; o_pr[id*3+2] = pr2;
        o_knn[id] = (float)idx;
        float v0 = lpb1[0] + lpw1[0]*pr0 + lpw1[1]*pr1 + lpw1[2]*pr2;
        float v1 = lpb1[1] + lpw1[3]*pr0 + lpw1[4]*pr1 + lpw1[5]*pr2;
        float v2 = lpb1[2] + lpw1[6]*pr0 + lpw1[7]*pr1 + lpw1[8]*pr2;
        ps0 += v0; ps1 += v1; ps2 += v2;
        pq0 += v0*v0; pq1 += v1*v1; pq2 += v2*v2;
        const float4* xg = (const float4*)(X1 + (size_t)idx * 16);
        #pragma unroll
        for (int h = 0; h < 4; ++h) {
            float4 v = xg[h];
            const float* wr = w1 + (4*h) * 67;
            e1s[e][4*h+0][tid] = fmaxf(v.x + wr[0]*pr0 + wr[1]*pr1 + wr[2]*pr2, 0.f);
            wr += 67;
            e1s[e][4*h+1][tid] = fmaxf(v.y + wr[0]*pr0 + wr[1]*pr1 + wr[2]*pr2, 0.f);
            wr += 67;
            e1s[e][4*h+2][tid] = fmaxf(v.z + wr[0]*pr0 + wr[1]*pr1 + wr[2]*pr2, 0.f);
            wr += 67;
            e1s[e][4*h+3][tid] = fmaxf(v.w + wr[0]*pr0 + wr[1]*pr1 + wr[2]*pr2, 0.f);
        }
    }
    __syncthreads();

    float acc_a[16], acc_b[16];
    #pragma unroll
    for (int o = 0; o < 16; ++o) { float bo = bb[o]; acc_a[o] = bo; acc_b[o] = bo; }

    int pair = 0;
    #pragma unroll 1
    for (int i = 0; i < 16; ++i) {
        float eai = e1s[0][i][tid];
        float ebi = e1s[1][i][tid];
        #pragma unroll 1
        for (int j = i; j < 16; ++j, ++pair) {
            float eaj = e1s[0][j][tid];
            float ebj = e1s[1][j][tid];
            float ma = eai * eaj, mb = ebi * ebj;
            const float4* wp = (const float4*)(wsym + pair * 16);
            float4 w0v = wp[0], w1v = wp[1], w2v = wp[2], w3v = wp[3];
            acc_a[0]  += w0v.x*ma; acc_a[1]  += w0v.y*ma; acc_a[2]  += w0v.z*ma; acc_a[3]  += w0v.w*ma;
            acc_a[4]  += w1v.x*ma; acc_a[5]  += w1v.y*ma; acc_a[6]  += w1v.z*ma; acc_a[7]  += w1v.w*ma;
            acc_a[8]  += w2v.x*ma; acc_a[9]  += w2v.y*ma; acc_a[10] += w2v.z*ma; acc_a[11] += w2v.w*ma;
            acc_a[12] += w3v.x*ma; acc_a[13] += w3v.y*ma; acc_a[14] += w3v.z*ma; acc_a[15] += w3v.w*ma;
            acc_b[0]  += w0v.x*mb; acc_b[1]  += w0v.y*mb; acc_b[2]  += w0v.z*mb; acc_b[3]  += w0v.w*mb;
            acc_b[4]  += w1v.x*mb; acc_b[5]  += w1v.y*mb; acc_b[6]  += w1v.z*mb; acc_b[7]  += w1v.w*mb;
            acc_b[8]  += w2v.x*mb; acc_b[9]  += w2v.y*mb; acc_b[10] += w2v.z*mb; acc_b[11] += w2v.w*mb;
            acc_b[12] += w3v.x*mb; acc_b[13] += w3v.y*mb; acc_b[14] += w3v.z*mb; acc_b[15] += w3v.w*mb;
        }
    }
    float4* eo = (float4*)(e_out + (size_t)id0 * 16);
    eo[0] = make_float4(acc_a[0],  acc_a[1],  acc_a[2],  acc_a[3]);
    eo[1] = make_float4(acc_a[4],  acc_a[5],  acc_a[6],  acc_a[7]);
    eo[2] = make_float4(acc_a[8],  acc_a[9],  acc_a[10], acc_a[11]);
    eo[3] = make_float4(acc_a[12], acc_a[13], acc_a[14], acc_a[15]);
    eo[4] = make_float4(acc_b[0],  acc_b[1],  acc_b[2],  acc_b[3]);
    eo[5] = make_float4(acc_b[4],  acc_b[5],  acc_b[6],  acc_b[7]);
    eo[6] = make_float4(acc_b[8],  acc_b[9],  acc_b[10], acc_b[11]);
    eo[7] = make_float4(acc_b[12], acc_b[13], acc_b[14], acc_b[15]);

    #pragma unroll
    for (int off = 32; off; off >>= 1) {
        ps0 += __shfl_xor(ps0, off); ps1 += __shfl_xor(ps1, off); ps2 += __shfl_xor(ps2, off);
        pq0 += __shfl_xor(pq0, off); pq1 += __shfl_xor(pq1, off); pq2 += __shfl_xor(pq2, off);
    }
    if ((tid & 63) == 0) {
        atomicAdd(&sb[0], ps0); atomicAdd(&sb[1], ps1); atomicAdd(&sb[2], ps2);
        atomicAdd(&sb[3], pq0); atomicAdd(&sb[4], pq1); atomicAdd(&sb[5], pq2);
    }
    __syncthreads();
    if (tid < 6) atomicAdd(&ws[WS_BNP_RAW + tid], sb[tid]);
}

__global__ void k_fin_bnp(float* __restrict__ ws,
    const float* __restrict__ g, const float* __restrict__ b,
    const float* __restrict__ lpw2, const float* __restrict__ lpb2)
{
    int t = threadIdx.x;
    if (t < 3) {
        float mean = ws[WS_BNP_RAW + t] / (float)NK;
        float var  = ws[WS_BNP_RAW + 3 + t] / (float)NK - mean * mean;
        float sc = g[t] * rsqrtf(var + 1e-5f);
        ws[WS_BNP_SS + t] = sc;
        ws[WS_BNP_SS + 3 + t] = b[t] - mean * sc;
    }
    if (t >= 16 && t < 64) {
        int r = t - 16, j = r / 3, d = r % 3;
        ws[WS_WS2 + r] = lpw2[(j)*3+d] + lpw2[(16+j)*3+d] + lpw2[(32+j)*3+d] + lpw2[(48+j)*3+d];
    }
    if (t >= 64 && t < 80) {
        int j = t - 64;
        ws[WS_WSB + j] = lpb2[j] + lpb2[16+j] + lpb2[32+j] + lpb2[48+j];
    }
}

// fold rank-3 p-shrink path into c1: per channel c,
// M[c][d] = sum_j c1w[c][16+j]*W2s[j][d], d_c = sum_j c1w[c][16+j]*wsb[j]
// stored as float4 {M0,M1,M2,d}. Also transpose c2 -> [c][8].
__global__ void k_fold(const float* __restrict__ c1w, const float* __restrict__ c2w,
                       float* __restrict__ ws)
{
    int c = threadIdx.x;
    if (c >= 64) return;
    const float* B = c1w + c * 32 + 16;
    float m0 = 0.f, m1 = 0.f, m2 = 0.f, dd = 0.f;
    #pragma unroll
    for (int j = 0; j < 16; ++j) {
        float bj = B[j];
        m0 += bj * ws[WS_WS2 + j*3 + 0];
        m1 += bj * ws[WS_WS2 + j*3 + 1];
        m2 += bj * ws[WS_WS2 + j*3 + 2];
        dd += bj * ws[WS_WSB + j];
    }
    ws[WS_C1F + c*4 + 0] = m0;
    ws[WS_C1F + c*4 + 1] = m1;
    ws[WS_C1F + c*4 + 2] = m2;
    ws[WS_C1F + c*4 + 3] = dd;
    #pragma unroll
    for (int k = 0; k < 8; ++k)
        ws[WS_C2T + c*8 + k] = c2w[k * 64 + c];
}

// load e[16] + q[3] for one element
__device__ __forceinline__ void build_eq(
    const float* __restrict__ e_in, const float* __restrict__ o_pr,
    const float* __restrict__ lpw1, const float* __restrict__ lpb1,
    const float* __restrict__ wsro, int id, float* e, float* q)
{
    const float4* ep = (const float4*)(e_in + (size_t)id * 16);
    #pragma unroll
    for (int i = 0; i < 4; ++i) {
        float4 v = ep[i];
        e[4*i] = v.x; e[4*i+1] = v.y; e[4*i+2] = v.z; e[4*i+3] = v.w;
    }
    float pr0 = o_pr[id*3+0], pr1 = o_pr[id*3+1], pr2 = o_pr[id*3+2];
    float v0 = lpb1[0] + lpw1[0]*pr0 + lpw1[1]*pr1 + lpw1[2]*pr2;
    float v1 = lpb1[1] + lpw1[3]*pr0 + lpw1[4]*pr1 + lpw1[5]*pr2;
    float v2 = lpb1[2] + lpw1[6]*pr0 + lpw1[7]*pr1 + lpw1[8]*pr2;
    q[0] = fmaxf(v0*wsro[WS_BNP_SS+0] + wsro[WS_BNP_SS+3], 0.f);
    q[1] = fmaxf(v1*wsro[WS_BNP_SS+1] + wsro[WS_BNP_SS+4], 0.f);
    q[2] = fmaxf(v2*wsro[WS_BNP_SS+2] + wsro[WS_BNP_SS+5], 0.f);
}

// BN1 stats: h1_c = A_c.e + M_c.q + d_c ; accumulate per-channel sum/ssq
__global__ __launch_bounds__(256) void k_stats1(
    const float* __restrict__ wsro, const float* __restrict__ out_ro,
    const float* __restrict__ lpw1, const float* __restrict__ lpb1,
    const float* __restrict__ c1w, float* __restrict__ ws)
{
    __shared__ float sacc[128];
    if (threadIdx.x < 128) sacc[threadIdx.x] = 0.f;
    __syncthreads();
    const float* e_in = wsro + WS_E;
    const float* o_pr = out_ro + OUT_PR;
    int id0 = blockIdx.x * 256 + threadIdx.x;
    int id1 = id0 + NK_STRIDE;
    float e0[16], e1[16], q0[3], q1[3];
    build_eq(e_in, o_pr, lpw1, lpb1, wsro, id0, e0, q0);
    build_eq(e_in, o_pr, lpw1, lpb1, wsro, id1, e1, q1);
    #pragma unroll 1
    for (int c = 0; c < 64; c += 2) {
        const float* wa = c1w + c * 32;        // A_c (first 16 of row)
        const float* wb = wa + 32;
        const float4 fa = *(const float4*)(wsro + WS_C1F + c*4);
        const float4 fb = *(const float4*)(wsro + WS_C1F + c*4 + 4);
        float hA0 = fa.w + fa.x*q0[0] + fa.y*q0[1] + fa.z*q0[2];
        float hB0 = fb.w + fb.x*q0[0] + fb.y*q0[1] + fb.z*q0[2];
        float hA1 = fa.w + fa.x*q1[0] + fa.y*q1[1] + fa.z*q1[2];
        float hB1 = fb.w + fb.x*q1[0] + fb.y*q1[1] + fb.z*q1[2];
        #pragma unroll
        for (int k = 0; k < 16; ++k) {
            hA0 += wa[k]*e0[k]; hB0 += wb[k]*e0[k];
            hA1 += wa[k]*e1[k]; hB1 += wb[k]*e1[k];
        }
        float sA = hA0 + hA1, qA = hA0*hA0 + hA1*hA1;
        float sB = hB0 + hB1, qB = hB0*hB0 + hB1*hB1;
        #pragma unroll
        for (int off = 32; off; off >>= 1) {
            sA += __shfl_xor(sA, off); qA += __shfl_xor(qA, off);
            sB += __shfl_xor(sB, off); qB += __shfl_xor(qB, off);
        }
        if ((threadIdx.x & 63) == 0) {
            atomicAdd(&sacc[c], sA);   atomicAdd(&sacc[64+c], qA);
            atomicAdd(&sacc[c+1], sB); atomicAdd(&sacc[65+c], qB);
        }
    }
    __syncthreads();
    if (threadIdx.x < 128) atomicAdd(&ws[WS_BN1_RAW + threadIdx.x], sacc[threadIdx.x]);
}

__global__ void k_fin_bn1(float* __restrict__ ws, const float* __restrict__ g, const float* __restrict__ b)
{
    int c = threadIdx.x;
    if (c < 64) {
        float mean = ws[WS_BN1_RAW + c] / (float)NK;
        float var  = ws[WS_BN1_RAW + 64 + c] / (float)NK - mean * mean;
        float sc = g[c] * rsqrtf(var + 1e-5f);
        ws[WS_BN1_SS + c] = sc;
        ws[WS_BN1_SS + 64 + c] = b[c] - mean * sc;
    }
}

// stage2: t2 = c2 @ relu(bn1(h1)), h1 via folded form; BN2 stats
__global__ __launch_bounds__(256) void k_stage2(
    const float* __restrict__ wsro, const float* __restrict__ out_ro,
    const float* __restrict__ lpw1, const float* __restrict__ lpb1,
    const float* __restrict__ c1w, float* __restrict__ ws)
{
    float tsum[8] = {0,0,0,0,0,0,0,0}, tssq[8] = {0,0,0,0,0,0,0,0};
    const float* e_in = wsro + WS_E;
    const float* o_pr = out_ro + OUT_PR;
    float* t2 = ws + WS_T2;
    int id = blockIdx.x * 256 + threadIdx.x;
    #pragma unroll 1
    for (int it = 0; it < 2; ++it, id += NK_STRIDE) {
        float e[16], q[3];
        build_eq(e_in, o_pr, lpw1, lpb1, wsro, id, e, q);
        float t2a[8] = {0,0,0,0,0,0,0,0};
        #pragma unroll 1
        for (int c = 0; c < 64; c += 2) {
            const float* wa = c1w + c * 32;
            const float* wb = wa + 32;
            const float4 fa = *(const float4*)(wsro + WS_C1F + c*4);
            const float4 fb = *(const float4*)(wsro + WS_C1F + c*4 + 4);
            float h0 = fa.w + fa.x*q[0] + fa.y*q[1] + fa.z*q[2];
            float h1 = fb.w + fb.x*q[0] + fb.y*q[1] + fb.z*q[2];
            #pragma unroll
            for (int k = 0; k < 16; ++k) {
                h0 += wa[k]*e[k]; h1 += wb[k]*e[k];
            }
            h0 = fmaxf(h0 * wsro[WS_BN1_SS + c]     + wsro[WS_BN1_SS + 64 + c], 0.f);
            h1 = fmaxf(h1 * wsro[WS_BN1_SS + c + 1] + wsro[WS_BN1_SS + 65 + c], 0.f);
            const float4 ca0 = *(const float4*)(wsro + WS_C2T + c*8);
            const float4 ca1 = *(const float4*)(wsro + WS_C2T + c*8 + 4);
            const float4 cb0 = *(const float4*)(wsro + WS_C2T + c*8 + 8);
            const float4 cb1 = *(const float4*)(wsro + WS_C2T + c*8 + 12);
            t2a[0] += h0*ca0.x + h1*cb0.x; t2a[1] += h0*ca0.y + h1*cb0.y;
            t2a[2] += h0*ca0.z + h1*cb0.z; t2a[3] += h0*ca0.w + h1*cb0.w;
            t2a[4] += h0*ca1.x + h1*cb1.x; t2a[5] += h0*ca1.y + h1*cb1.y;
            t2a[6] += h0*ca1.z + h1*cb1.z; t2a[7] += h0*ca1.w + h1*cb1.w;
        }
        float4* t2p = (float4*)(t2 + (size_t)id * 8);
        t2p[0] = make_float4(t2a[0], t2a[1], t2a[2], t2a[3]);
        t2p[1] = make_float4(t2a[4], t2a[5], t2a[6], t2a[7]);
        #pragma unroll
        for (int c2 = 0; c2 < 8; ++c2) { tsum[c2] += t2a[c2]; tssq[c2] += t2a[c2] * t2a[c2]; }
    }
    __shared__ float sacc[16];
    if (threadIdx.x < 16) sacc[threadIdx.x] = 0.f;
    __syncthreads();
    #pragma unroll
    for (int c2 = 0; c2 < 8; ++c2) {
        float s = tsum[c2], s2 = tssq[c2];
        #pragma unroll
        for (int off = 32; off; off >>= 1) { s += __shfl_xor(s, off); s2 += __shfl_xor(s2, off); }
        if ((threadIdx.x & 63) == 0) { atomicAdd(&sacc[c2], s); atomicAdd(&sacc[8 + c2], s2); }
    }
    __syncthreads();
    if (threadIdx.x < 16) atomicAdd(&ws[WS_BN2_RAW + threadIdx.x], sacc[threadIdx.x]);
}

__global__ void k_fin_bn2(float* __restrict__ ws, const float* __restrict__ g, const float* __restrict__ b)
{
    int c = threadIdx.x;
    if (c < 8) {
        float mean = ws[WS_BN2_RAW + c] / (float)NK;
        float var  = ws[WS_BN2_RAW + 8 + c] / (float)NK - mean * mean;
        float sc = g[c] * rsqrtf(var + 1e-5f);
        ws[WS_BN2_SS + c] = sc;
        ws[WS_BN2_SS + 8 + c] = b[c] - mean * sc;
    }
}

__global__ __launch_bounds__(128) void k_final(
    const int* __restrict__ knn, const float* __restrict__ wsro,
    const float* __restrict__ c3w, const float* __restrict__ c3b,
    const float* __restrict__ lpw1, const float* __restrict__ lpb1,
    const float* __restrict__ lpw2, const float* __restrict__ lpb2,
    float* __restrict__ out)
{
    int n = blockIdx.x, t = threadIdx.x;
    __shared__ float h2s[16][8], ssm[16][8], wls[16][8], pes[16][3], prs[48], red[128];
    __shared__ int idxs[16];
    const float* t2   = wsro + WS_T2;
    const float* o_pr = out + OUT_PR;
    const float* xrow = wsro + WS_XROW;
    if (t < 16) idxs[t] = knn[n * 16 + t];
    if (t < 48) prs[t] = o_pr[(size_t)n * 48 + t];
    {
        int k = t >> 3, c2 = t & 7;
        float v = t2[(size_t)n * 128 + t];
        h2s[k][c2] = fmaxf(v * wsro[WS_BN2_SS + c2] + wsro[WS_BN2_SS + 8 + c2], 0.f);
    }
    __syncthreads();
    if (t < 48) {
        int k = t / 3, d = t % 3;
        float pe = lpb1[d] + lpw1[d*3+0]*prs[k*3+0] + lpw1[d*3+1]*prs[k*3+1] + lpw1[d*3+2]*prs[k*3+2];
        pes[k][d] = fmaxf(pe * wsro[WS_BNP_SS + d] + wsro[WS_BNP_SS + 3 + d], 0.f);
    }
    {
        int k = t >> 3, cc = t & 7;
        float s = c3b[cc];
        #pragma unroll
        for (int q = 0; q < 8; ++q) s += h2s[k][q] * c3w[cc * 8 + q];
        ssm[k][cc] = s;
    }
    __syncthreads();
    if (t < 8) {
        float m = -1e30f;
        for (int k = 0; k < 16; ++k) m = fmaxf(m, ssm[k][t]);
        float sum = 0.f;
        for (int k = 0; k < 16; ++k) { float ev = __expf(ssm[k][t] - m); wls[k][t] = ev; sum += ev; }
        float inv = 1.f / sum;
        for (int k = 0; k < 16; ++k) wls[k][t] *= inv;
    }
    __syncthreads();
    int c = t & 63, kh = t >> 6;
    float w20 = lpw2[c*3], w21 = lpw2[c*3+1], w22 = lpw2[c*3+2], bc = lpb2[c];
    float acc = 0.f;
    float* out_xk = out + OUT_XK + (size_t)n * 1024;
    #pragma unroll
    for (int i = 0; i < 8; ++i) {
        int k = kh * 8 + i;
        float xv = xrow[(size_t)idxs[k] * 64 + c];
        float pemb = bc + w20 * pes[k][0] + w21 * pes[k][1] + w22 * pes[k][2];
        float val = (xv + pemb) * wls[k][c & 7];
        out_xk[k * 64 + c] = val;
        acc += val;
    }
    red[t] = acc;
    __syncthreads();
    if (t < 64) out[(size_t)n * 64 + t] = red[t] + red[t + 64];
}

// ---------------- launch ----------------
extern "C" void kernel_launch(void* const* d_in, const int* in_sizes, int n_in,
                              void* d_out, int out_size, void* d_ws, size_t ws_size,
                              hipStream_t stream)
{
    (void)in_sizes; (void)n_in; (void)out_size; (void)ws_size;
    const float* p    = (const float*)d_in[0];
    const float* x    = (const float*)d_in[1];
    const int*   knn  = (const int*)  d_in[2];
    const float* w1   = (const float*)d_in[3];
    const float* b1   = (const float*)d_in[4];
    const float* bw   = (const float*)d_in[5];
    const float* bb   = (const float*)d_in[6];
    const float* lpw1 = (const float*)d_in[7];
    const float* lpb1 = (const float*)d_in[8];
    const float* bnpg = (const float*)d_in[9];
    const float* bnpb = (const float*)d_in[10];
    const float* lpw2 = (const float*)d_in[11];
    const float* lpb2 = (const float*)d_in[12];
    const float* c1w  = (const float*)d_in[13];
    const float* bn1g = (const float*)d_in[14];
    const float* bn1b = (const float*)d_in[15];
    const float* c2w  = (const float*)d_in[16];
    const float* bn2g = (const float*)d_in[17];
    const float* bn2b = (const float*)d_in[18];
    const float* c3w  = (const float*)d_in[19];
    const float* c3b  = (const float*)d_in[20];
    const float* w3   = (const float*)d_in[21];
    const float* b3   = (const float*)d_in[22];
    float* out = (float*)d_out;
    float* ws  = (float*)d_ws;

    (void)hipMemsetAsync(ws, 0, 160 * sizeof(float), stream);
    k_pre   <<<(NPTS + 255) / 256, 256, 0, stream>>>(x, w3, b3, w1, b1, ws);
    k_sym   <<<9, 256, 0, stream>>>(bw, ws);
    k_stage0<<<GRID_NK, 256, 0, stream>>>(p, knn, w1, bb, lpw1, lpb1, ws, ws, out);
    k_fin_bnp<<<1, 128, 0, stream>>>(ws, bnpg, bnpb, lpw2, lpb2);
    k_fold  <<<1, 64, 0, stream>>>(c1w, c2w, ws);
    k_stats1<<<GRID_NK, 256, 0, stream>>>(ws, out, lpw1, lpb1, c1w, ws);
    k_fin_bn1<<<1, 64, 0, stream>>>(ws, bn1g, bn1b);
    k_stage2<<<GRID_NK, 256, 0, stream>>>(ws, out, lpw1, lpb1, c1w, ws);
    k_fin_bn2<<<1, 64, 0, stream>>>(ws, bn2g, bn2b);
    k_final <<<NPTS, 128, 0, stream>>>(knn, ws, c3w, c3b, lpw1, lpb1, lpw2, lpb2, out);
}